// Round 11
// baseline (32.008 us; speedup 1.0000x reference)
//
#include <hip/hip_runtime.h>
#include <math.h>

// ---------------------------------------------------------------------------
// RISVQCLayer: angles = tanh(fused @ W^T + b) * pi  -> 4-qubit VQC -> (z+1)*pi
// B=65536, HID=256, R=16 runs (64 outputs/sample), fp32 in/out.
//
// R10: SINGLE fused kernel (no prep launch, no d_ws). 2048 blocks x 256 thr,
// 32-sample tiles (R7 structure, best so far). Per-block operand prep runs
// in the HBM-load shadow:
//  - lane (l4,l15) computes column l15 of U_{4cg+l4} (circuit, ~420 VALU;
//    layer-0-on-basis as outer product), parks in LDS (pad-20 rows), and
//    waves assemble the verified [U_hi;U_lo] split-fp16 ua fragments in-wave.
//  - af W-fragments loaded fragment-ordered from global W (L2-hot) + cvt.
//  - bias folded into MFMA acc init.
//  - Ucols region ALIASES the fused-tile region (all Ucols reads complete
//    before barrier #1; tile written after) -> LDS 28.7 KB total.
// GEMM (16x16x32, XOR-swizzled LDS B-frags), Phase A (tanh->sincos->factor
// tab, wave-private), Phase B (one mfma_32x32x16 per run, hi/lo combine
// in-lane, single shfl_xor(32) reduce) identical to R7 (verified).
// ---------------------------------------------------------------------------

#define PI_F 3.14159265358979323846f

typedef _Float16 f16x4 __attribute__((ext_vector_type(4)));
typedef _Float16 f16x8 __attribute__((ext_vector_type(8)));
typedef float    f32x4 __attribute__((ext_vector_type(4)));
typedef float    f32x16 __attribute__((ext_vector_type(16)));

__device__ __forceinline__ void ry_gate(float st[16], float c, float s, int w) {
    const int m = 1 << (3 - w);
    #pragma unroll
    for (int i = 0; i < 16; ++i) {
        if (i & m) continue;
        float a = st[i];
        float b = st[i | m];
        st[i]     = c * a - s * b;
        st[i | m] = s * a + c * b;
    }
}

__device__ __forceinline__ void cnot_gate(float st[16], int cw, int tw) {
    const int cm = 1 << (3 - cw);
    const int tm = 1 << (3 - tw);
    #pragma unroll
    for (int i = 0; i < 16; ++i) {
        if ((i & cm) && !(i & tm)) {
            float tmp = st[i];
            st[i] = st[i | tm];
            st[i | tm] = tmp;
        }
    }
}

__global__ __launch_bounds__(256, 4) void vqc_fused_kernel(
        const float* __restrict__ fused,   // (65536, 256)
        const float* __restrict__ W,       // (64, 256)
        const float* __restrict__ bp,      // (64,)
        const float* __restrict__ vw,      // (16, 4, 4)
        float* __restrict__ out) {         // (65536, 64)
    // [0,20480): Ucols fp32 [wave][run][16 rows][20]  (prologue only)
    // [0,16384): fused tile fp16 swizzled             (after barrier #1)
    // [20480,28672): tab fp16 [16 runs][32 samples][8]
    __shared__ __align__(16) char smem[28672];
    float*    Ucols = (float*)smem;
    _Float16* tab   = (_Float16*)(smem + 20480);

    const int tid  = threadIdx.x;
    const int lane = tid & 63;
    const int cg   = tid >> 6;             // wave id = run group
    const int l15  = lane & 15;
    const int l4   = lane >> 4;
    const size_t b0 = (size_t)blockIdx.x * 32;

    // ---- 1. issue fused tile loads (HBM, longest latency) ----
    float4 stg[8];
    {
        const float4* s4 = (const float4*)(fused + b0 * 256);
        #pragma unroll
        for (int it = 0; it < 8; ++it) stg[it] = s4[tid + it * 256];
    }

    // ---- 2. circuit: column j=l15 of U_{r_own}, under the load shadow ----
    const int r_own = 4 * cg + l4;
    const float* vwr = vw + r_own * 16;
    float st[16];
    {
        // layer 0 applied to basis e_j: product state (outer product)
        float4 th = *(const float4*)vwr;
        float c, s;
        float f0a, f0b, f1a, f1b, f2a, f2b, f3a, f3b;
        __sincosf(th.x * 0.5f, &s, &c);
        if ((l15 >> 3) & 1) { f0a = -s; f0b = c; } else { f0a = c; f0b = s; }
        __sincosf(th.y * 0.5f, &s, &c);
        if ((l15 >> 2) & 1) { f1a = -s; f1b = c; } else { f1a = c; f1b = s; }
        __sincosf(th.z * 0.5f, &s, &c);
        if ((l15 >> 1) & 1) { f2a = -s; f2b = c; } else { f2a = c; f2b = s; }
        __sincosf(th.w * 0.5f, &s, &c);
        if (l15 & 1)        { f3a = -s; f3b = c; } else { f3a = c; f3b = s; }
        float a01[4] = {f0a * f1a, f0a * f1b, f0b * f1a, f0b * f1b};
        float a23[4] = {f2a * f3a, f2a * f3b, f2b * f3a, f2b * f3b};
        #pragma unroll
        for (int hi = 0; hi < 4; ++hi)
            #pragma unroll
            for (int lo = 0; lo < 4; ++lo)
                st[hi * 4 + lo] = a01[hi] * a23[lo];
    }
    cnot_gate(st, 0, 1);
    cnot_gate(st, 2, 3);
    {
        float4 th = *(const float4*)(vwr + 4);
        float c, s;
        __sincosf(th.x * 0.5f, &s, &c); ry_gate(st, c, s, 0);
        __sincosf(th.y * 0.5f, &s, &c); ry_gate(st, c, s, 1);
        __sincosf(th.z * 0.5f, &s, &c); ry_gate(st, c, s, 2);
        __sincosf(th.w * 0.5f, &s, &c); ry_gate(st, c, s, 3);
    }
    cnot_gate(st, 1, 2);
    cnot_gate(st, 3, 0);
    {
        float4 th = *(const float4*)(vwr + 8);
        float c, s;
        __sincosf(th.x * 0.5f, &s, &c); ry_gate(st, c, s, 0);
        __sincosf(th.y * 0.5f, &s, &c); ry_gate(st, c, s, 1);
        __sincosf(th.z * 0.5f, &s, &c); ry_gate(st, c, s, 2);
        __sincosf(th.w * 0.5f, &s, &c); ry_gate(st, c, s, 3);
    }
    cnot_gate(st, 0, 1);
    cnot_gate(st, 1, 2);
    cnot_gate(st, 2, 3);
    cnot_gate(st, 3, 0);
    {
        float4 th = *(const float4*)(vwr + 12);
        float c, s;
        __sincosf(th.x * 0.5f, &s, &c); ry_gate(st, c, s, 0);
        __sincosf(th.y * 0.5f, &s, &c); ry_gate(st, c, s, 1);
        __sincosf(th.z * 0.5f, &s, &c); ry_gate(st, c, s, 2);
        __sincosf(th.w * 0.5f, &s, &c); ry_gate(st, c, s, 3);
    }

    // ---- 3. park columns, assemble ua fragments (same-wave, no barrier) ----
    {
        float* myU = Ucols + cg * 1280 + l4 * 320;   // this lane's run region
        #pragma unroll
        for (int i = 0; i < 16; ++i) myU[i * 20 + l15] = st[i];
    }
    f16x8 ua[4];
    {
        const int selo = (lane >> 4) & 1;  // (lane&31) >= 16 -> lo part
        const int hbit = lane >> 5;        // k-half selector
        #pragma unroll
        for (int rr = 0; rr < 4; ++rr) {
            const float* up = Ucols + cg * 1280 + rr * 320 + l15 * 20 + 8 * hbit;
            float4 u0 = *(const float4*)up;
            float4 u1 = *(const float4*)(up + 4);
            float uu[8] = {u0.x, u0.y, u0.z, u0.w, u1.x, u1.y, u1.z, u1.w};
            #pragma unroll
            for (int e = 0; e < 8; ++e) {
                _Float16 hi = (_Float16)uu[e];
                _Float16 lo = (_Float16)(uu[e] - (float)hi);
                ua[rr][e] = selo ? lo : hi;
            }
        }
    }

    // ---- 4. W fragments direct from global (L2-hot) + cvt, and bias ----
    f16x8 af[8];
    {
        const float* Wr = W + (size_t)(cg * 16 + l15) * 256;
        #pragma unroll
        for (int kk = 0; kk < 8; ++kk) {
            const float* wp = Wr + (kk * 4 + l4) * 8;
            float4 w0 = *(const float4*)wp;
            float4 w1 = *(const float4*)(wp + 4);
            f16x8 h;
            h[0] = (_Float16)w0.x; h[1] = (_Float16)w0.y;
            h[2] = (_Float16)w0.z; h[3] = (_Float16)w0.w;
            h[4] = (_Float16)w1.x; h[5] = (_Float16)w1.y;
            h[6] = (_Float16)w1.z; h[7] = (_Float16)w1.w;
            af[kk] = h;
        }
    }
    float4 bb = *(const float4*)(bp + 4 * r_own);   // bias for lane's angles

    __syncthreads();   // barrier #1: all Ucols reads done; tile region free

    // ---- 5. staging convert stg -> tile fp16, XOR-swizzled ----
    #pragma unroll
    for (int it = 0; it < 8; ++it) {
        int q = tid + it * 256;            // float4 index within tile
        float4 v = stg[it];
        int row = q >> 6;
        int c4  = (q & 63) << 2;
        int sl  = (c4 >> 3) ^ (row & 7);
        int byteoff = row * 512 + (sl << 4) + ((c4 & 7) << 1);
        f16x4 h = { (_Float16)v.x, (_Float16)v.y, (_Float16)v.z, (_Float16)v.w };
        *(f16x4*)(smem + byteoff) = h;
    }
    __syncthreads();   // barrier #2: tile ready

    // ---- 6. GEMM: acc[sg][j] = pre (bias folded into acc init) ----
    f32x4 acc[2];
    acc[0][0] = bb.x; acc[0][1] = bb.y; acc[0][2] = bb.z; acc[0][3] = bb.w;
    acc[1] = acc[0];
    #pragma unroll
    for (int kk = 0; kk < 8; ++kk) {
        int slot = kk * 4 + l4;
        #pragma unroll
        for (int sg = 0; sg < 2; ++sg) {
            int frow = sg * 16 + l15;
            f16x8 bf = *(const f16x8*)(smem + frow * 512 + ((slot ^ (frow & 7)) << 4));
            acc[sg] = __builtin_amdgcn_mfma_f32_16x16x32_f16(af[kk], bf, acc[sg], 0, 0, 0);
        }
    }

    // ---- 7. Phase A: tanh->sincos->factor table (wave-private) ----
    #pragma unroll
    for (int sg = 0; sg < 2; ++sg) {
        float cc[4], ssn[4];
        #pragma unroll
        for (int w = 0; w < 4; ++w) {
            float pre = acc[sg][w];
            float e   = __expf(2.f * pre);
            float th  = __fdividef(e - 1.f, e + 1.f);   // tanh(pre)
            float ha  = th * (0.5f * PI_F);             // theta/2
            __sincosf(ha, &ssn[w], &cc[w]);
        }
        f16x8 tt;
        tt[0] = (_Float16)(cc[0] * cc[1]);  tt[1] = (_Float16)(cc[0] * ssn[1]);
        tt[2] = (_Float16)(ssn[0] * cc[1]); tt[3] = (_Float16)(ssn[0] * ssn[1]);
        tt[4] = (_Float16)(cc[2] * cc[3]);  tt[5] = (_Float16)(cc[2] * ssn[3]);
        tt[6] = (_Float16)(ssn[2] * cc[3]); tt[7] = (_Float16)(ssn[2] * ssn[3]);
        *(f16x8*)(tab + (r_own * 32 + sg * 16 + l15) * 8) = tt;
    }
    // tab region [4cg..4cg+3] written & read by wave cg only -> no barrier.

    // ---- 8. Phase B: per run ONE mfma_32x32x16 over all 32 samples ----
    const int   s32 = lane & 31;           // sample within tile
    const int   hh  = lane >> 5;           // state half (bit2 of state)
    const float g1  = hh ? -1.f : 1.f;

    #pragma unroll
    for (int rr = 0; rr < 4; ++rr) {
        const int r = 4 * cg + rr;
        f16x8 tt = *(const f16x8*)(tab + (r * 32 + s32) * 8);
        _Float16 a0 = tt[2 * hh], a1 = tt[2 * hh + 1];
        f16x8 se;
        se[0] = a0 * tt[4]; se[1] = a0 * tt[5];
        se[2] = a0 * tt[6]; se[3] = a0 * tt[7];
        se[4] = a1 * tt[4]; se[5] = a1 * tt[5];
        se[6] = a1 * tt[6]; se[7] = a1 * tt[7];

        f32x16 zero = {};
        f32x16 o = __builtin_amdgcn_mfma_f32_32x32x16_f16(ua[rr], se, zero, 0, 0, 0);

        // combine hi/lo: full state s' = (j&3)+8*(j>>2)+4*hh, j=0..7
        float p[8];
        #pragma unroll
        for (int j = 0; j < 8; ++j) {
            float of = o[j] + o[j + 8];
            p[j] = of * of;
        }
        float a = p[0] + p[1], b = p[2] + p[3];
        float c = p[4] + p[5], d = p[6] + p[7];
        float ab = a + b, cd = c + d;
        float z0 = ab - cd;                 // bit3 sign
        float z1 = g1 * (ab + cd);          // bit2 = hh
        float z2 = (a - b) + (c - d);       // bit1
        float z3 = (p[0] - p[1] + p[2] - p[3]) + (p[4] - p[5] + p[6] - p[7]);

        z0 += __shfl_xor(z0, 32);
        z1 += __shfl_xor(z1, 32);
        z2 += __shfl_xor(z2, 32);
        z3 += __shfl_xor(z3, 32);

        if (hh == 0) {
            float4 ov;
            ov.x = (z0 + 1.f) * PI_F;
            ov.y = (z1 + 1.f) * PI_F;
            ov.z = (z2 + 1.f) * PI_F;
            ov.w = (z3 + 1.f) * PI_F;
            *(float4*)(out + (b0 + s32) * 64 + 4 * r) = ov;
        }
    }
}

extern "C" void kernel_launch(void* const* d_in, const int* in_sizes, int n_in,
                              void* d_out, int out_size, void* d_ws, size_t ws_size,
                              hipStream_t stream) {
    const float* fused = (const float*)d_in[0];   // (65536, 256)
    const float* Wp    = (const float*)d_in[1];   // (64, 256)
    const float* bp    = (const float*)d_in[2];   // (64,)
    const float* vw    = (const float*)d_in[3];   // (16, 4, 4)
    float* out = (float*)d_out;                   // (65536, 64)

    const int B = 65536;
    vqc_fused_kernel<<<B / 32, 256, 0, stream>>>(fused, Wp, bp, vw, out);
}

// Round 12
// 28.920 us; speedup vs baseline: 1.1068x; 1.1068x over previous
//
#include <hip/hip_runtime.h>
#include <math.h>

// ---------------------------------------------------------------------------
// RISVQCLayer: angles = tanh(fused @ W^T + b) * pi  -> 4-qubit VQC -> (z+1)*pi
// B=65536, HID=256, R=16 runs (64 outputs/sample), fp32 in/out.
//
// R11 = R7 + full-residency layout (fix for the measured 30%-of-62% occupancy
// quantization: work = 8 blocks/CU but only 5-6 could co-reside).
//  - tab ALIASES the fused-tile LDS (tile dead after GEMM; barrier #2 added)
//    -> LDS 16.4 KB.
//  - __launch_bounds__(256,8) caps VGPR at 64 -> 8 blocks/CU resident =
//    exactly the per-CU work -> single uniform round, no tail.
//  - To fit 64 VGPR: af W-fragments loaded inside the GEMM loop (L2-hot),
//    ua at Phase B, bias at Phase A; only the HBM tile loads are prefetched.
// GEMM (16x16x32, XOR-swizzled LDS B-frags), Phase A (tanh->sincos->factor
// tab), Phase B (one mfma_32x32x16 per run, [U_hi;U_lo] split fp16, hi/lo
// combine in-lane, single shfl_xor(32)) identical to R7 (verified).
// d_ws: [0,32K) Wf fp16 frags; [32K,48K) UA32 fp16 frags; [48K,64K) U fp32.
// ---------------------------------------------------------------------------

#define PI_F 3.14159265358979323846f

typedef _Float16 f16x4 __attribute__((ext_vector_type(4)));
typedef _Float16 f16x8 __attribute__((ext_vector_type(8)));
typedef float    f32x4 __attribute__((ext_vector_type(4)));
typedef float    f32x16 __attribute__((ext_vector_type(16)));

__device__ __forceinline__ void ry_gate(float st[16], float c, float s, int w) {
    const int m = 1 << (3 - w);
    #pragma unroll
    for (int i = 0; i < 16; ++i) {
        if (i & m) continue;
        float a = st[i];
        float b = st[i | m];
        st[i]     = c * a - s * b;
        st[i | m] = s * a + c * b;
    }
}

__device__ __forceinline__ void cnot_gate(float st[16], int cw, int tw) {
    const int cm = 1 << (3 - cw);
    const int tm = 1 << (3 - tw);
    #pragma unroll
    for (int i = 0; i < 16; ++i) {
        if ((i & cm) && !(i & tm)) {
            float tmp = st[i];
            st[i] = st[i | tm];
            st[i | tm] = tmp;
        }
    }
}

// prep: block0 -> U matrices then UA32 fragments; block1 -> W frags.
// (layouts verified R3-R9)
__global__ void prep_kernel(const float* __restrict__ vw,
                            const float* __restrict__ W,
                            char* __restrict__ ws) {
    const int tid = threadIdx.x;   // 256
    if (blockIdx.x == 0) {
        float* Ut = (float*)(ws + 49152);          // fp32 U[r][i][j]
        {   // phase 1: thread (r, j) computes column j of U_r
            const int r = tid >> 4, j = tid & 15;
            const float* wr = vw + r * 16;
            float cs[16], sn[16];
            #pragma unroll
            for (int i = 0; i < 16; ++i) {
                float h = wr[i] * 0.5f;
                cs[i] = __cosf(h);
                sn[i] = __sinf(h);
            }
            float st[16];
            #pragma unroll
            for (int i = 0; i < 16; ++i) st[i] = 0.f;
            st[j] = 1.f;
            #pragma unroll
            for (int w = 0; w < 4; ++w) ry_gate(st, cs[w], sn[w], w);
            cnot_gate(st, 0, 1);
            cnot_gate(st, 2, 3);
            #pragma unroll
            for (int w = 0; w < 4; ++w) ry_gate(st, cs[4 + w], sn[4 + w], w);
            cnot_gate(st, 1, 2);
            cnot_gate(st, 3, 0);
            #pragma unroll
            for (int w = 0; w < 4; ++w) ry_gate(st, cs[8 + w], sn[8 + w], w);
            cnot_gate(st, 0, 1);
            cnot_gate(st, 1, 2);
            cnot_gate(st, 2, 3);
            cnot_gate(st, 3, 0);
            #pragma unroll
            for (int w = 0; w < 4; ++w) ry_gate(st, cs[12 + w], sn[12 + w], w);
            #pragma unroll
            for (int i = 0; i < 16; ++i) Ut[r * 256 + i * 16 + j] = st[i];
        }
        __syncthreads();
        {   // phase 2: UA32[r][lane]: i=lane&31, h=lane>>5, k=8h+e (K=16):
            //          i<16 -> hi(U[i][k]); i>=16 -> lo(U[i-16][k])
            _Float16* UA = (_Float16*)(ws + 32768);
            #pragma unroll
            for (int t = 0; t < 4; ++t) {
                int f = t * 256 + tid;             // 0..1023
                int r = f >> 6, lane = f & 63;
                int i = lane & 31, hh = lane >> 5;
                const float* urow = Ut + r * 256 + (i & 15) * 16;
                f16x8 h;
                #pragma unroll
                for (int e = 0; e < 8; ++e) {
                    float u = urow[8 * hh + e];
                    if (i < 16) {
                        h[e] = (_Float16)u;
                    } else {
                        _Float16 hi = (_Float16)u;
                        h[e] = (_Float16)(u - (float)hi);
                    }
                }
                *(f16x8*)(UA + f * 8) = h;
            }
        }
    } else {
        // W fragments: row=cg*16+l15, k=(kk*4+l4)*8+e
        _Float16* Wh = (_Float16*)ws;
        #pragma unroll
        for (int t = 0; t < 8; ++t) {
            int f  = tid * 8 + t;            // fragment id 0..2047
            int cg = f >> 9;
            int kk = (f >> 6) & 7;
            int l  = f & 63;
            int row = cg * 16 + (l & 15);
            int k0  = (kk * 4 + (l >> 4)) * 8;
            const float* src = W + row * 256 + k0;
            f16x8 h;
            #pragma unroll
            for (int e = 0; e < 8; ++e) h[e] = (_Float16)src[e];
            *(f16x8*)(Wh + f * 8) = h;
        }
    }
}

__global__ __launch_bounds__(256, 8) void vqc_main_kernel(
        const float* __restrict__ fused,   // (65536, 256)
        const char* __restrict__ ws,       // Wf + UA32 fragments
        const float* __restrict__ bp,      // (64,)
        float* __restrict__ out) {         // (65536, 64)
    // [0,16384): fused tile fp16 swizzled (32 rows x 512B) DURING GEMM;
    //            after barrier #2 the first 8KB is reused as tab.
    __shared__ __align__(16) char smem[16384];
    _Float16* tab = (_Float16*)smem;       // [16 runs][32 samples] x8 fp16

    const int tid  = threadIdx.x;
    const int lane = tid & 63;
    const int cg   = tid >> 6;             // wave id = run group
    const int l15  = lane & 15;
    const int l4   = lane >> 4;
    const size_t b0 = (size_t)blockIdx.x * 32;

    // ---- prologue: issue fused tile loads (HBM, longest latency) ----
    float4 stg[8];
    {
        const float4* s4 = (const float4*)(fused + b0 * 256);
        #pragma unroll
        for (int it = 0; it < 8; ++it) stg[it] = s4[tid + it * 256];
    }

    // ---- stage convert stg -> tile fp16, XOR-swizzled ----
    #pragma unroll
    for (int it = 0; it < 8; ++it) {
        int q = tid + it * 256;            // float4 index within tile
        float4 v = stg[it];
        int row = q >> 6;
        int c4  = (q & 63) << 2;
        int sl  = (c4 >> 3) ^ (row & 7);
        int byteoff = row * 512 + (sl << 4) + ((c4 & 7) << 1);
        f16x4 h = { (_Float16)v.x, (_Float16)v.y, (_Float16)v.z, (_Float16)v.w };
        *(f16x4*)(smem + byteoff) = h;
    }
    __syncthreads();                       // barrier #1: tile ready

    // ---- GEMM: acc[sg][j] = pre[sample sg*16+l15][angle 16cg+4l4+j] ----
    // af fragments streamed from L2 inside the loop (VGPR budget), TLP-hidden.
    const f16x8* Wf = (const f16x8*)ws;
    f32x4 acc[2] = {};
    #pragma unroll
    for (int kk = 0; kk < 8; ++kk) {
        f16x8 af = Wf[(cg * 8 + kk) * 64 + lane];
        int slot = kk * 4 + l4;
        #pragma unroll
        for (int sg = 0; sg < 2; ++sg) {
            int frow = sg * 16 + l15;
            f16x8 bf = *(const f16x8*)(smem + frow * 512 + ((slot ^ (frow & 7)) << 4));
            acc[sg] = __builtin_amdgcn_mfma_f32_16x16x32_f16(af, bf, acc[sg], 0, 0, 0);
        }
    }
    __syncthreads();                       // barrier #2: tile dead; tab aliases

    // ---- Phase A: lane owns run r_own; factor table (wave-private slots) ----
    const int r_own = 4 * cg + l4;
    {
        float4 bb = *(const float4*)(bp + 4 * r_own);
        #pragma unroll
        for (int sg = 0; sg < 2; ++sg) {
            float bias[4] = {bb.x, bb.y, bb.z, bb.w};
            float cc[4], ssn[4];
            #pragma unroll
            for (int w = 0; w < 4; ++w) {
                float pre = acc[sg][w] + bias[w];
                float e   = __expf(2.f * pre);
                float th  = __fdividef(e - 1.f, e + 1.f);   // tanh(pre)
                float ha  = th * (0.5f * PI_F);             // theta/2
                __sincosf(ha, &ssn[w], &cc[w]);
            }
            f16x8 tt;
            tt[0] = (_Float16)(cc[0] * cc[1]);  tt[1] = (_Float16)(cc[0] * ssn[1]);
            tt[2] = (_Float16)(ssn[0] * cc[1]); tt[3] = (_Float16)(ssn[0] * ssn[1]);
            tt[4] = (_Float16)(cc[2] * cc[3]);  tt[5] = (_Float16)(cc[2] * ssn[3]);
            tt[6] = (_Float16)(ssn[2] * cc[3]); tt[7] = (_Float16)(ssn[2] * ssn[3]);
            *(f16x8*)(tab + (r_own * 32 + sg * 16 + l15) * 8) = tt;
        }
    }
    // tab region [4cg..4cg+3] written & read by wave cg only -> no barrier.

    // ---- Phase B: per run ONE mfma_32x32x16 over all 32 samples ----
    const f16x8* UA = (const f16x8*)(ws + 32768);
    const int   s32 = lane & 31;           // sample within tile
    const int   hh  = lane >> 5;           // state half (bit2 of state)
    const float g1  = hh ? -1.f : 1.f;

    #pragma unroll
    for (int rr = 0; rr < 4; ++rr) {
        const int r = 4 * cg + rr;
        f16x8 ua = UA[r * 64 + lane];      // L2-hot, TLP-hidden
        f16x8 tt = *(const f16x8*)(tab + (r * 32 + s32) * 8);
        _Float16 a0 = tt[2 * hh], a1 = tt[2 * hh + 1];
        f16x8 se;
        se[0] = a0 * tt[4]; se[1] = a0 * tt[5];
        se[2] = a0 * tt[6]; se[3] = a0 * tt[7];
        se[4] = a1 * tt[4]; se[5] = a1 * tt[5];
        se[6] = a1 * tt[6]; se[7] = a1 * tt[7];

        f32x16 zero = {};
        f32x16 o = __builtin_amdgcn_mfma_f32_32x32x16_f16(ua, se, zero, 0, 0, 0);

        // combine hi/lo: full state s' = (j&3)+8*(j>>2)+4*hh, j=0..7
        float p[8];
        #pragma unroll
        for (int j = 0; j < 8; ++j) {
            float of = o[j] + o[j + 8];
            p[j] = of * of;
        }
        float a = p[0] + p[1], b = p[2] + p[3];
        float c = p[4] + p[5], d = p[6] + p[7];
        float ab = a + b, cd = c + d;
        float z0 = ab - cd;                 // bit3 sign
        float z1 = g1 * (ab + cd);          // bit2 = hh
        float z2 = (a - b) + (c - d);       // bit1
        float z3 = (p[0] - p[1] + p[2] - p[3]) + (p[4] - p[5] + p[6] - p[7]);

        z0 += __shfl_xor(z0, 32);
        z1 += __shfl_xor(z1, 32);
        z2 += __shfl_xor(z2, 32);
        z3 += __shfl_xor(z3, 32);

        if (hh == 0) {
            float4 ov;
            ov.x = (z0 + 1.f) * PI_F;
            ov.y = (z1 + 1.f) * PI_F;
            ov.z = (z2 + 1.f) * PI_F;
            ov.w = (z3 + 1.f) * PI_F;
            *(float4*)(out + (b0 + s32) * 64 + 4 * r) = ov;
        }
    }
}

extern "C" void kernel_launch(void* const* d_in, const int* in_sizes, int n_in,
                              void* d_out, int out_size, void* d_ws, size_t ws_size,
                              hipStream_t stream) {
    const float* fused = (const float*)d_in[0];   // (65536, 256)
    const float* Wp    = (const float*)d_in[1];   // (64, 256)
    const float* bp    = (const float*)d_in[2];   // (64,)
    const float* vw    = (const float*)d_in[3];   // (16, 4, 4)
    float* out = (float*)d_out;                   // (65536, 64)
    char*  ws  = (char*)d_ws;                     // 64 KB used

    prep_kernel<<<2, 256, 0, stream>>>(vw, Wp, ws);

    const int B = 65536;
    vqc_main_kernel<<<B / 32, 256, 0, stream>>>(fused, ws, bp, out);
}

// Round 13
// 26.831 us; speedup vs baseline: 1.1929x; 1.0779x over previous
//
#include <hip/hip_runtime.h>
#include <math.h>

// ---------------------------------------------------------------------------
// RISVQCLayer: angles = tanh(fused @ W^T + b) * pi  -> 4-qubit VQC -> (z+1)*pi
// B=65536, HID=256, R=16 runs (64 outputs/sample), fp32 in/out.
//
// R12 = R7 (best, 26.6us) + two independent, low-risk deltas:
//  - tab ALIASES the fused-tile LDS (tile dead after GEMM; barrier #2 added,
//    verified correct in R11) -> LDS 24.5 -> 16.4 KB.
//  - __launch_bounds__(256,4): cap VGPR at 128 WITH all prefetches hoisted
//    (R11 showed de-hoisting af costs ~1us/block; R7's bounds(256,3) allowed
//    VGPR >128 -> possibly only 2 blocks/CU). 16 waves/CU guaranteed.
//  - prologue order: HBM tile loads first, then L2 prefetches (af/ua/bb).
// GEMM (16x16x32, XOR-swizzled LDS B-frags), Phase A (tanh->sincos->factor
// tab, wave-private), Phase B (one mfma_32x32x16 per run, [U_hi;U_lo] split
// fp16 = exact U, hi/lo combine in-lane, single shfl_xor(32)) all verified.
// d_ws: [0,32K) Wf fp16 frags; [32K,48K) UA32 fp16 frags; [48K,64K) U fp32.
// ---------------------------------------------------------------------------

#define PI_F 3.14159265358979323846f

typedef _Float16 f16x4 __attribute__((ext_vector_type(4)));
typedef _Float16 f16x8 __attribute__((ext_vector_type(8)));
typedef float    f32x4 __attribute__((ext_vector_type(4)));
typedef float    f32x16 __attribute__((ext_vector_type(16)));

__device__ __forceinline__ void ry_gate(float st[16], float c, float s, int w) {
    const int m = 1 << (3 - w);
    #pragma unroll
    for (int i = 0; i < 16; ++i) {
        if (i & m) continue;
        float a = st[i];
        float b = st[i | m];
        st[i]     = c * a - s * b;
        st[i | m] = s * a + c * b;
    }
}

__device__ __forceinline__ void cnot_gate(float st[16], int cw, int tw) {
    const int cm = 1 << (3 - cw);
    const int tm = 1 << (3 - tw);
    #pragma unroll
    for (int i = 0; i < 16; ++i) {
        if ((i & cm) && !(i & tm)) {
            float tmp = st[i];
            st[i] = st[i | tm];
            st[i | tm] = tmp;
        }
    }
}

// prep: block0 -> U matrices then UA32 fragments; block1 -> W frags.
// (layouts verified R3-R11)
__global__ void prep_kernel(const float* __restrict__ vw,
                            const float* __restrict__ W,
                            char* __restrict__ ws) {
    const int tid = threadIdx.x;   // 256
    if (blockIdx.x == 0) {
        float* Ut = (float*)(ws + 49152);          // fp32 U[r][i][j]
        {   // phase 1: thread (r, j) computes column j of U_r
            const int r = tid >> 4, j = tid & 15;
            const float* wr = vw + r * 16;
            float cs[16], sn[16];
            #pragma unroll
            for (int i = 0; i < 16; ++i) {
                float h = wr[i] * 0.5f;
                cs[i] = __cosf(h);
                sn[i] = __sinf(h);
            }
            float st[16];
            #pragma unroll
            for (int i = 0; i < 16; ++i) st[i] = 0.f;
            st[j] = 1.f;
            #pragma unroll
            for (int w = 0; w < 4; ++w) ry_gate(st, cs[w], sn[w], w);
            cnot_gate(st, 0, 1);
            cnot_gate(st, 2, 3);
            #pragma unroll
            for (int w = 0; w < 4; ++w) ry_gate(st, cs[4 + w], sn[4 + w], w);
            cnot_gate(st, 1, 2);
            cnot_gate(st, 3, 0);
            #pragma unroll
            for (int w = 0; w < 4; ++w) ry_gate(st, cs[8 + w], sn[8 + w], w);
            cnot_gate(st, 0, 1);
            cnot_gate(st, 1, 2);
            cnot_gate(st, 2, 3);
            cnot_gate(st, 3, 0);
            #pragma unroll
            for (int w = 0; w < 4; ++w) ry_gate(st, cs[12 + w], sn[12 + w], w);
            #pragma unroll
            for (int i = 0; i < 16; ++i) Ut[r * 256 + i * 16 + j] = st[i];
        }
        __syncthreads();
        {   // phase 2: UA32[r][lane]: i=lane&31, h=lane>>5, k=8h+e (K=16):
            //          i<16 -> hi(U[i][k]); i>=16 -> lo(U[i-16][k])
            _Float16* UA = (_Float16*)(ws + 32768);
            #pragma unroll
            for (int t = 0; t < 4; ++t) {
                int f = t * 256 + tid;             // 0..1023
                int r = f >> 6, lane = f & 63;
                int i = lane & 31, hh = lane >> 5;
                const float* urow = Ut + r * 256 + (i & 15) * 16;
                f16x8 h;
                #pragma unroll
                for (int e = 0; e < 8; ++e) {
                    float u = urow[8 * hh + e];
                    if (i < 16) {
                        h[e] = (_Float16)u;
                    } else {
                        _Float16 hi = (_Float16)u;
                        h[e] = (_Float16)(u - (float)hi);
                    }
                }
                *(f16x8*)(UA + f * 8) = h;
            }
        }
    } else {
        // W fragments: row=cg*16+l15, k=(kk*4+l4)*8+e
        _Float16* Wh = (_Float16*)ws;
        #pragma unroll
        for (int t = 0; t < 8; ++t) {
            int f  = tid * 8 + t;            // fragment id 0..2047
            int cg = f >> 9;
            int kk = (f >> 6) & 7;
            int l  = f & 63;
            int row = cg * 16 + (l & 15);
            int k0  = (kk * 4 + (l >> 4)) * 8;
            const float* src = W + row * 256 + k0;
            f16x8 h;
            #pragma unroll
            for (int e = 0; e < 8; ++e) h[e] = (_Float16)src[e];
            *(f16x8*)(Wh + f * 8) = h;
        }
    }
}

__global__ __launch_bounds__(256, 4) void vqc_main_kernel(
        const float* __restrict__ fused,   // (65536, 256)
        const char* __restrict__ ws,       // Wf + UA32 fragments
        const float* __restrict__ bp,      // (64,)
        float* __restrict__ out) {         // (65536, 64)
    // [0,16384): fused tile fp16 swizzled (32 rows x 512B) during GEMM;
    //            after barrier #2 the first 8KB is reused as tab.
    __shared__ __align__(16) char smem[16384];
    _Float16* tab = (_Float16*)smem;       // [16 runs][32 samples] x8 fp16

    const int tid  = threadIdx.x;
    const int lane = tid & 63;
    const int cg   = tid >> 6;             // wave id = run group
    const int l15  = lane & 15;
    const int l4   = lane >> 4;
    const size_t b0 = (size_t)blockIdx.x * 32;

    // ---- 1. issue fused tile loads FIRST (HBM, longest latency) ----
    float4 stg[8];
    {
        const float4* s4 = (const float4*)(fused + b0 * 256);
        #pragma unroll
        for (int it = 0; it < 8; ++it) stg[it] = s4[tid + it * 256];
    }

    // ---- 2. hoisted L2 prefetches: af / ua / bias (R7-style) ----
    const f16x8* Wf = (const f16x8*)ws;
    f16x8 af[8];
    #pragma unroll
    for (int kk = 0; kk < 8; ++kk) af[kk] = Wf[(cg * 8 + kk) * 64 + lane];

    const f16x8* UA = (const f16x8*)(ws + 32768);
    f16x8 ua[4];
    #pragma unroll
    for (int rr = 0; rr < 4; ++rr) ua[rr] = UA[(4 * cg + rr) * 64 + lane];

    float4 bb = *(const float4*)(bp + 4 * (4 * cg + l4));   // lane's run bias

    // ---- 3. stage convert stg -> tile fp16, XOR-swizzled ----
    #pragma unroll
    for (int it = 0; it < 8; ++it) {
        int q = tid + it * 256;            // float4 index within tile
        float4 v = stg[it];
        int row = q >> 6;
        int c4  = (q & 63) << 2;
        int sl  = (c4 >> 3) ^ (row & 7);
        int byteoff = row * 512 + (sl << 4) + ((c4 & 7) << 1);
        f16x4 h = { (_Float16)v.x, (_Float16)v.y, (_Float16)v.z, (_Float16)v.w };
        *(f16x4*)(smem + byteoff) = h;
    }
    __syncthreads();                       // barrier #1: tile ready

    // ---- 4. GEMM: acc[sg][j] = pre[sample sg*16+l15][angle 16cg+4l4+j] ----
    f32x4 acc[2] = {};
    #pragma unroll
    for (int kk = 0; kk < 8; ++kk) {
        int slot = kk * 4 + l4;
        #pragma unroll
        for (int sg = 0; sg < 2; ++sg) {
            int frow = sg * 16 + l15;
            f16x8 bf = *(const f16x8*)(smem + frow * 512 + ((slot ^ (frow & 7)) << 4));
            acc[sg] = __builtin_amdgcn_mfma_f32_16x16x32_f16(af[kk], bf, acc[sg], 0, 0, 0);
        }
    }
    __syncthreads();                       // barrier #2: tile dead; tab aliases

    // ---- 5. Phase A: lane owns run r_own; factor table (wave-private) ----
    const int r_own = 4 * cg + l4;
    #pragma unroll
    for (int sg = 0; sg < 2; ++sg) {
        float bias[4] = {bb.x, bb.y, bb.z, bb.w};
        float cc[4], ssn[4];
        #pragma unroll
        for (int w = 0; w < 4; ++w) {
            float pre = acc[sg][w] + bias[w];
            float e   = __expf(2.f * pre);
            float th  = __fdividef(e - 1.f, e + 1.f);   // tanh(pre)
            float ha  = th * (0.5f * PI_F);             // theta/2
            __sincosf(ha, &ssn[w], &cc[w]);
        }
        f16x8 tt;
        tt[0] = (_Float16)(cc[0] * cc[1]);  tt[1] = (_Float16)(cc[0] * ssn[1]);
        tt[2] = (_Float16)(ssn[0] * cc[1]); tt[3] = (_Float16)(ssn[0] * ssn[1]);
        tt[4] = (_Float16)(cc[2] * cc[3]);  tt[5] = (_Float16)(cc[2] * ssn[3]);
        tt[6] = (_Float16)(ssn[2] * cc[3]); tt[7] = (_Float16)(ssn[2] * ssn[3]);
        *(f16x8*)(tab + (r_own * 32 + sg * 16 + l15) * 8) = tt;
    }
    // tab region [4cg..4cg+3] written & read by wave cg only -> no barrier.

    // ---- 6. Phase B: per run ONE mfma_32x32x16 over all 32 samples ----
    const int   s32 = lane & 31;           // sample within tile
    const int   hh  = lane >> 5;           // state half (bit2 of state)
    const float g1  = hh ? -1.f : 1.f;

    #pragma unroll
    for (int rr = 0; rr < 4; ++rr) {
        const int r = 4 * cg + rr;
        f16x8 tt = *(const f16x8*)(tab + (r * 32 + s32) * 8);
        _Float16 a0 = tt[2 * hh], a1 = tt[2 * hh + 1];
        f16x8 se;
        se[0] = a0 * tt[4]; se[1] = a0 * tt[5];
        se[2] = a0 * tt[6]; se[3] = a0 * tt[7];
        se[4] = a1 * tt[4]; se[5] = a1 * tt[5];
        se[6] = a1 * tt[6]; se[7] = a1 * tt[7];

        f32x16 zero = {};
        f32x16 o = __builtin_amdgcn_mfma_f32_32x32x16_f16(ua[rr], se, zero, 0, 0, 0);

        // combine hi/lo: full state s' = (j&3)+8*(j>>2)+4*hh, j=0..7
        float p[8];
        #pragma unroll
        for (int j = 0; j < 8; ++j) {
            float of = o[j] + o[j + 8];
            p[j] = of * of;
        }
        float a = p[0] + p[1], b = p[2] + p[3];
        float c = p[4] + p[5], d = p[6] + p[7];
        float ab = a + b, cd = c + d;
        float z0 = ab - cd;                 // bit3 sign
        float z1 = g1 * (ab + cd);          // bit2 = hh
        float z2 = (a - b) + (c - d);       // bit1
        float z3 = (p[0] - p[1] + p[2] - p[3]) + (p[4] - p[5] + p[6] - p[7]);

        z0 += __shfl_xor(z0, 32);
        z1 += __shfl_xor(z1, 32);
        z2 += __shfl_xor(z2, 32);
        z3 += __shfl_xor(z3, 32);

        if (hh == 0) {
            float4 ov;
            ov.x = (z0 + 1.f) * PI_F;
            ov.y = (z1 + 1.f) * PI_F;
            ov.z = (z2 + 1.f) * PI_F;
            ov.w = (z3 + 1.f) * PI_F;
            *(float4*)(out + (b0 + s32) * 64 + 4 * r) = ov;
        }
    }
}

extern "C" void kernel_launch(void* const* d_in, const int* in_sizes, int n_in,
                              void* d_out, int out_size, void* d_ws, size_t ws_size,
                              hipStream_t stream) {
    const float* fused = (const float*)d_in[0];   // (65536, 256)
    const float* Wp    = (const float*)d_in[1];   // (64, 256)
    const float* bp    = (const float*)d_in[2];   // (64,)
    const float* vw    = (const float*)d_in[3];   // (16, 4, 4)
    float* out = (float*)d_out;                   // (65536, 64)
    char*  ws  = (char*)d_ws;                     // 64 KB used

    prep_kernel<<<2, 256, 0, stream>>>(vw, Wp, ws);

    const int B = 65536;
    vqc_main_kernel<<<B / 32, 256, 0, stream>>>(fused, ws, bp, out);
}